// Round 6
// baseline (94.587 us; speedup 1.0000x reference)
//
#include <hip/hip_runtime.h>
#include <hip/hip_bf16.h>

// CapsuleLayer dynamic routing, MI355X. fp32 in/out.
// C=10, B=128, N=1152, IN=8, OUT=16, 3 routing iters.
//
// v14 (round 16): G=1, P ENTIRELY in registers, LDS = 640 B combine buffer.
//   Evidence chain: v11 (755 MB cache traffic) == v13 (378 MB) == ~42 us ->
//   bytes NOT binding. v13's 29% occ = grid supply (640 blk = 2.5/CU), not a
//   cap -> time scales with total work: measured VALU ~15 us + estimated
//   DS-pipe ~10-15 us/CU (ldsP traffic + shfl + combine, ~255-345 instr/wave)
//   with poor overlap. v13 proved register-P works: 9xuint2 + full unroll +
//   sched_barrier(0) separators -> VGPR 52, no spill, no hoist balloon.
//   v14 drops LDS-P entirely: kills 36 ldsP DS ops/wave, restores the
//   1280-block grid (40 waves/CU supply), cap = VGPR only (expect ~60 ->
//   8 waves/SIMD = 32/CU, 2x v11's residency). W loads i-halved (4 float4
//   live) to keep peak ~60 VGPR. W traffic back to 755 MB - proven free.
//   Falsifier: >=38 us at occ>=55 + no spill -> plateau is the shfl/exp/
//   combine core; attack butterfly structure next or concede floor.
//
// Structure: 512 thr = 8 waves, one block per (c,b), 1280 blocks.
//   Lane l: o-quad q=l&3 (owns o=q*4..+3), row-sub rsub=l>>2; wave w covers
//   rows [w*144,(w+1)*144) in 9 passes of 16. W float4 load = 16 rows x 64 B
//   fully-consumed lines. fp32 accumulation; P storage bf16x2 in 18 VGPRs
//   (absmax 0.0078, threshold 0.0172). Logit state eliminated: logit =
//   dot(oa, P) recomputed per iter (quad butterfly, 2 shfl). Unnormalized
//   softmax (|logit| <~30, fp32-safe). Iter-0 sums fused into priors.
//   XCD-chunked swizzle: 1280 = 8 x 160 bijective, per-XCD W ws ~1.2 MB.

constexpr int C = 10, B = 128, N = 1152, IN = 8, OUT = 16;
constexpr int THREADS = 512;
constexpr int NW = THREADS / 64;          // 8 waves
constexpr int PASSES = N / (NW * 16);     // 9
constexpr int NBLK = C * B;               // 1280
constexpr int NXCD = 8;
constexpr int CHUNK = NBLK / NXCD;        // 160 (1280 % 8 == 0: bijective)

__device__ __forceinline__ unsigned packbf(float a, float b) {
    __hip_bfloat162 h = __float22bfloat162_rn(float2{a, b});  // RNE
    return *(unsigned*)&h;
}
__device__ __forceinline__ float bflo(unsigned u) { return __uint_as_float(u << 16); }
__device__ __forceinline__ float bfhi(unsigned u) { return __uint_as_float(u & 0xffff0000u); }

__global__ __launch_bounds__(THREADS)
void caps_route(const float* __restrict__ Xf, const float* __restrict__ Wf,
                float* __restrict__ Of) {
    // combine buffer: [w][0..15] = s4 by o, [16] = ssum, [17..19] pad
    __shared__ float lds_c[NW][20];                    // 640 B

    const int t = threadIdx.x;
    const int l = t & 63;
    const int wid = t >> 6;
    const int q = l & 3;        // o-quad: owns o = q*4 .. q*4+3
    const int rsub = l >> 2;    // row-sub within a pass (0..15)

    // XCD-chunked swizzle: physical bid%8 -> XCD (round-robin dispatch).
    const int bid = blockIdx.x;
    const int blk = (bid & (NXCD - 1)) * CHUNK + (bid >> 3);
    const int c = blk >> 7;     // 128 consecutive logical blocks share c
    const int b = blk & 127;

    // ---- priors: P[n][o] = sum_i x[b,n,i] * W[c,n,i,o]
    // P -> 18 VGPRs (9 x uint2 bf16x2, statically indexed). Fully unrolled
    // with sched_barrier(0) pass separators (v13-proven: no hoist balloon).
    // Fused iter-0 sums (logits all 0 -> uniform softmax -> plain sums).
    uint2 Pr[PASSES];
    float s40[4] = {0.f, 0.f, 0.f, 0.f};
    const int nbase = wid * (16 * PASSES) + rsub;
    #pragma unroll
    for (int p = 0; p < PASSES; ++p) {
        const int n = nbase + p * 16;
        const float4* wr = (const float4*)(Wf + (size_t)(c * N + n) * (IN * OUT)) + q;
        const float4* xr = (const float4*)(Xf + (size_t)(b * N + n) * IN);
        float a0, a1, a2, a3;
        {   // i = 0..3
            const float4 xa = xr[0];
            const float4 u0 = wr[0], u1 = wr[4], u2 = wr[8], u3 = wr[12];
            a0 = xa.x * u0.x; a1 = xa.x * u0.y; a2 = xa.x * u0.z; a3 = xa.x * u0.w;
            a0 = fmaf(xa.y, u1.x, a0); a1 = fmaf(xa.y, u1.y, a1);
            a2 = fmaf(xa.y, u1.z, a2); a3 = fmaf(xa.y, u1.w, a3);
            a0 = fmaf(xa.z, u2.x, a0); a1 = fmaf(xa.z, u2.y, a1);
            a2 = fmaf(xa.z, u2.z, a2); a3 = fmaf(xa.z, u2.w, a3);
            a0 = fmaf(xa.w, u3.x, a0); a1 = fmaf(xa.w, u3.y, a1);
            a2 = fmaf(xa.w, u3.z, a2); a3 = fmaf(xa.w, u3.w, a3);
        }
        {   // i = 4..7
            const float4 xc = xr[1];
            const float4 u0 = wr[16], u1 = wr[20], u2 = wr[24], u3 = wr[28];
            a0 = fmaf(xc.x, u0.x, a0); a1 = fmaf(xc.x, u0.y, a1);
            a2 = fmaf(xc.x, u0.z, a2); a3 = fmaf(xc.x, u0.w, a3);
            a0 = fmaf(xc.y, u1.x, a0); a1 = fmaf(xc.y, u1.y, a1);
            a2 = fmaf(xc.y, u1.z, a2); a3 = fmaf(xc.y, u1.w, a3);
            a0 = fmaf(xc.z, u2.x, a0); a1 = fmaf(xc.z, u2.y, a1);
            a2 = fmaf(xc.z, u2.z, a2); a3 = fmaf(xc.z, u2.w, a3);
            a0 = fmaf(xc.w, u3.x, a0); a1 = fmaf(xc.w, u3.y, a1);
            a2 = fmaf(xc.w, u3.z, a2); a3 = fmaf(xc.w, u3.w, a3);
        }
        s40[0] += a0; s40[1] += a1; s40[2] += a2; s40[3] += a3;
        Pr[p] = uint2{packbf(a0, a1), packbf(a2, a3)};
        __builtin_amdgcn_sched_barrier(0);   // no cross-pass load hoisting
    }

    // accumulated output quad-slice (fp32); logit[p] == dot(oa_full16, P[p])
    float oa[4] = {0.f, 0.f, 0.f, 0.f};

    // ---- dynamic routing ----
    for (int it = 0; it < 3; ++it) {
        float s4[4];
        float ssum;
        if (it == 0) {
            ssum = (float)PASSES;
            #pragma unroll
            for (int k = 0; k < 4; ++k) s4[k] = s40[k];
        } else {
            ssum = 0.f;
            #pragma unroll
            for (int k = 0; k < 4; ++k) s4[k] = 0.f;
            #pragma unroll
            for (int p = 0; p < PASSES; ++p) {
                const uint2 v = Pr[p];            // register P: pure VALU
                const float p0 = bflo(v.x), p1 = bfhi(v.x);
                const float p2 = bflo(v.y), p3 = bfhi(v.y);
                float d = oa[0] * p0;
                d = fmaf(oa[1], p1, d);
                d = fmaf(oa[2], p2, d);
                d = fmaf(oa[3], p3, d);
                d += __shfl_xor(d, 1, 64);
                d += __shfl_xor(d, 2, 64);
                const float e = __expf(d);        // replicated across quad
                ssum += e;
                s4[0] = fmaf(e, p0, s4[0]);
                s4[1] = fmaf(e, p1, s4[1]);
                s4[2] = fmaf(e, p2, s4[2]);
                s4[3] = fmaf(e, p3, s4[3]);
            }
        }
        // reduce across the 16 row-subs of the wave (masks 4..32; quad bits
        // 0,1 carry replicas (ssum) / distinct o (s4) -> not summed)
        #pragma unroll
        for (int m = 4; m < 64; m <<= 1) {
            ssum += __shfl_xor(ssum, m, 64);
            #pragma unroll
            for (int k = 0; k < 4; ++k) s4[k] += __shfl_xor(s4[k], m, 64);
        }
        if (l < 4) {  // lane l == quad q: owns o = l*4..l*4+3
            #pragma unroll
            for (int k = 0; k < 4; ++k) lds_c[wid][l * 4 + k] = s4[k];
        }
        if (l == 0) lds_c[wid][16] = ssum;
        __syncthreads();   // A: combine buffer ready

        // all-thread redundant combine + squash (each thread: its own o-quad).
        // lds_c reads: 4 distinct 16B addrs/wave -> 16-lane broadcast, free.
        float a0 = 0.f, a1 = 0.f, a2 = 0.f, a3 = 0.f, S = 0.f;
        #pragma unroll
        for (int w = 0; w < NW; ++w) {
            const float4 v = *(const float4*)&lds_c[w][q * 4];
            a0 += v.x; a1 += v.y; a2 += v.z; a3 += v.w;
            S += lds_c[w][16];
        }
        const float inv = 1.f / S;
        const float s0 = a0 * inv, s1 = a1 * inv;
        const float s2 = a2 * inv, s3 = a3 * inv;
        float r = s0 * s0 + s1 * s1 + s2 * s2 + s3 * s3;
        r += __shfl_xor(r, 1, 64);
        r += __shfl_xor(r, 2, 64);
        const float sc = r / ((1.f + r) * sqrtf(r + 1e-8f));
        if (it < 2) {
            __syncthreads();   // B: combine reads done before next writes
            oa[0] += s0 * sc; oa[1] += s1 * sc;
            oa[2] += s2 * sc; oa[3] += s3 * sc;
        } else if (t < 4) {  // wid==0, rsub==0, q==t: write final outputs
            Of[((size_t)c * B + b) * OUT + q * 4 + 0] = s0 * sc;
            Of[((size_t)c * B + b) * OUT + q * 4 + 1] = s1 * sc;
            Of[((size_t)c * B + b) * OUT + q * 4 + 2] = s2 * sc;
            Of[((size_t)c * B + b) * OUT + q * 4 + 3] = s3 * sc;
        }
    }
}

extern "C" void kernel_launch(void* const* d_in, const int* in_sizes, int n_in,
                              void* d_out, int out_size, void* d_ws, size_t ws_size,
                              hipStream_t stream) {
    const float* X = (const float*)d_in[0];   // [B,N,IN] fp32
    const float* W = (const float*)d_in[1];   // [C,N,IN,OUT] fp32
    float* O = (float*)d_out;                 // [C,B,OUT] fp32
    hipLaunchKernelGGL(caps_route, dim3(NBLK), dim3(THREADS), 0, stream, X, W, O);
}